// Round 9
// baseline (83.635 us; speedup 1.0000x reference)
//
#include <hip/hip_runtime.h>
#include <hip/hip_bf16.h>

// CAM: out = (q @ k^T) @ v + v  ==  q @ (k^T @ v) + v.   S[b] = k^T v is 49x49.
// Two kernels, pure-bf16 MFMA (RNE; absmax 8.0 vs threshold 27.68 at R8):
//   ktv : NO LDS, 1 MFMA/chunk, barrier-free streaming (R8-proven).
//   qs  : fused sred+qs. Stage q-tile transposed in LDS (kills the 64-line
//         global gather), reduce Spart->bf16 St[n][m] in LDS (L2-hot, shared
//         by 16 blocks/batch), one barrier, 4 uniform MFMA chunks, coalesced
//         stores. Removes the sred launch + 11 MB HBM round-trip.
// A/B k-slot invariance: both operands indexed by kc*16+g*8+e, so any k-slot
// permutation assumption cancels. C/D map HW-validated (R7/R8 passes).

#define BATCH  128
#define CH     1024
#define NN     49
#define LDQ    65     // f32 stride of Qt rows (conflict-free)
#define LDS_T  72     // bf16 stride of St rows: 144 B -> 16-B aligned b128 reads

typedef short  bf16x8 __attribute__((ext_vector_type(8)));
typedef float  f32x16 __attribute__((ext_vector_type(16)));

__device__ __forceinline__ short f2bf(float x) {
  return __builtin_bit_cast(short, __float2bfloat16(x));   // RNE; pairs to cvt_pk
}

// ---------------- Kernel 1: Spart[b*split+s] = K-chunk^T @ V-chunk ----------
__global__ __launch_bounds__(256) void ktv_kernel(
    const float* __restrict__ Kg, const float* __restrict__ Vg,
    float* __restrict__ Spart, int split, int nchunks) {
  const int blk  = blockIdx.x;
  const int b    = blk / split;
  const int s    = blk - b * split;
  const int tid  = threadIdx.x;
  const int wv   = tid >> 6;
  const int lane = tid & 63;
  const int g    = lane >> 5;
  const int ln   = lane & 31;
  const int i0   = (wv >> 1) * 32;
  const int j0   = (wv & 1)  * 32;
  const int rowA = min(i0 + ln, NN - 1);   // clamp: dup loads, rows discarded
  const int rowB = min(j0 + ln, NN - 1);

  const size_t cbase = ((size_t)b * CH + (size_t)s * (nchunks * 16)) * NN;
  const float* Ka = Kg + cbase + (size_t)(g * 8) * NN + rowA;
  const float* Vb = Vg + cbase + (size_t)(g * 8) * NN + rowB;

  f32x16 acc;
  #pragma unroll
  for (int r = 0; r < 16; ++r) acc[r] = 0.f;

  #pragma unroll 2
  for (int kc = 0; kc < nchunks; ++kc) {
    const float* ka = Ka + (size_t)kc * 16 * NN;
    const float* vb = Vb + (size_t)kc * 16 * NN;
    float kx[8], vx[8];
    #pragma unroll
    for (int e = 0; e < 8; ++e) { kx[e] = ka[e * NN]; vx[e] = vb[e * NN]; }
    bf16x8 ah, bh;
    #pragma unroll
    for (int e = 0; e < 8; ++e) { ah[e] = f2bf(kx[e]); bh[e] = f2bf(vx[e]); }
    acc = __builtin_amdgcn_mfma_f32_32x32x16_bf16(ah, bh, acc, 0, 0, 0);
  }

  // C/D: col = lane&31, row = (r&3) + 8*(r>>2) + 4*(lane>>5)   [m74/m101]
  float* Sp = Spart + (size_t)blk * (NN * NN);
  const int j = j0 + ln;
  if (j < NN) {
    #pragma unroll
    for (int r = 0; r < 16; ++r) {
      const int i = i0 + (r & 3) + 8 * (r >> 2) + 4 * g;
      if (i < NN) Sp[i * NN + j] = acc[r];
    }
  }
}

// ------ Kernel 2: out[64-row tile] = q @ (sum_s Spart) + v   (fused) --------
__global__ __launch_bounds__(256) void qs_kernel(
    const float* __restrict__ Qg, const float* __restrict__ Vg,
    const float* __restrict__ Spart, float* __restrict__ Og, int split) {
  const int blk  = blockIdx.x;            // 2048 = 128 batches x 16 row-tiles
  const int b    = blk >> 4;
  const int rt   = blk & 15;
  const int tid  = threadIdx.x;
  const int wv   = tid >> 6;
  const int lane = tid & 63;
  const int g    = lane >> 5;
  const int ln   = lane & 31;
  const int i0   = (wv >> 1) * 32;
  const int j0   = (wv & 1)  * 32;

  __shared__ float Qt[64 * LDQ];                        // 16.6 KB
  __shared__ __align__(16) unsigned short St[64 * LDS_T]; // 9.0 KB

  // ---- stage q transposed: Qt[m][r] = q[r0+r][m]; coalesced reads ----
  const size_t qbase = ((size_t)b * CH + (size_t)rt * 64) * NN;
  for (int idx = tid; idx < 64 * NN; idx += 256) {
    const int r = idx / NN, m = idx - r * NN;
    Qt[m * LDQ + r] = Qg[qbase + idx];
  }
  for (int idx = tid; idx < (64 - NN) * LDQ; idx += 256)   // zero pad m=49..63
    Qt[NN * LDQ + idx] = 0.f;

  // ---- reduce split partials -> St[n][m] bf16, zero-padded ----
  const float* Sp = Spart + (size_t)b * split * (NN * NN);
  for (int e = tid; e < 64 * 64; e += 256) {
    const int m = e >> 6, n = e & 63;     // m-major: coalesced global reads
    float v = 0.f;
    if (m < NN && n < NN) {
      for (int s = 0; s < split; ++s)
        v += Sp[(size_t)s * (NN * NN) + m * NN + n];
    }
    St[n * LDS_T + m] = (unsigned short)f2bf(v);
  }
  __syncthreads();

  // ---- 4 uniform MFMA chunks (zero-padded: no tail masking) ----
  const unsigned short* stb = &St[(j0 + ln) * LDS_T];   // 16-B aligned rows
  const int colQ = i0 + ln;                             // all 64 rows valid
  f32x16 acc;
  #pragma unroll
  for (int r = 0; r < 16; ++r) acc[r] = 0.f;

  #pragma unroll
  for (int kc = 0; kc < 4; ++kc) {
    const int m0 = kc * 16 + g * 8;
    bf16x8 ah;
    #pragma unroll
    for (int e = 0; e < 8; ++e)
      ah[e] = f2bf(Qt[(m0 + e) * LDQ + colQ]);          // lane-consecutive LDS
    const bf16x8 bh = *(const bf16x8*)&stb[m0];         // one ds_read_b128
    acc = __builtin_amdgcn_mfma_f32_32x32x16_bf16(ah, bh, acc, 0, 0, 0);
  }

  // ---- store: all 64 rows valid; guard only col j < 49; coalesced per r ----
  const int j = j0 + ln;
  if (j < NN) {
    #pragma unroll
    for (int r = 0; r < 16; ++r) {
      const int i = i0 + (r & 3) + 8 * (r >> 2) + 4 * g;
      const size_t off = qbase + (size_t)i * NN + j;
      Og[off] = acc[r] + Vg[off];
    }
  }
}

extern "C" void kernel_launch(void* const* d_in, const int* in_sizes, int n_in,
                              void* d_out, int out_size, void* d_ws, size_t ws_size,
                              hipStream_t stream) {
  (void)in_sizes; (void)n_in; (void)out_size;
  const float* v1 = (const float*)d_in[0];
  const float* q1 = (const float*)d_in[1];
  const float* k1 = (const float*)d_in[2];
  float* out = (float*)d_out;

  int split = 8;                           // spart: 9.83 MB at split=8
  while (split > 1 && (size_t)BATCH * split * NN * NN * 4 > ws_size)
    split >>= 1;
  const int nchunks = CH / (split * 16);

  float* spart = (float*)d_ws;

  ktv_kernel<<<dim3(BATCH * split), dim3(256), 0, stream>>>(k1, v1, spart, split, nchunks);
  qs_kernel<<<dim3(BATCH * 16), dim3(256), 0, stream>>>(q1, v1, spart, out, split);
}

// Round 10
// 51.398 us; speedup vs baseline: 1.6272x; 1.6272x over previous
//
#include <hip/hip_runtime.h>
#include <hip/hip_bf16.h>

// CAM: out = (q @ k^T) @ v + v  ==  q @ (k^T @ v) + v.   S[b] = k^T v is 49x49.
// Three kernels, pure-bf16 MFMA (RNE; absmax 8.0 vs threshold 27.68):
//   ktv : NO LDS, 1 MFMA/chunk, barrier-free; fragment loads are lane-
//         contiguous 128-B segments (proven ~<=11us wall via R9 attribution).
//   sred: partial-sum -> St = S^T bf16, zero-padded [64][64] per batch.
//   qs  : A-path = q staged TRANSPOSED in LDS (coalesced global reads; kills
//         the 64-line/instr row-gather of R8), B-path = bf16 St 16-B global
//         loads (L2-hot). 2 row-tiles per block, one barrier, 4 blocks/CU.
// R9 lesson: do NOT re-reduce S per qs block (16x redundant + LDS conflicts).

#define BATCH  128
#define CH     1024
#define NN     49
#define LDQ    65     // f32 stride of Qt rows (conflict-free transpose)

typedef short  bf16x8 __attribute__((ext_vector_type(8)));
typedef float  f32x16 __attribute__((ext_vector_type(16)));

__device__ __forceinline__ short f2bf(float x) {
  return __builtin_bit_cast(short, __float2bfloat16(x));   // RNE; pairs to cvt_pk
}

// ---------------- Kernel 1: Spart[b*split+s] = K-chunk^T @ V-chunk ----------
__global__ __launch_bounds__(256) void ktv_kernel(
    const float* __restrict__ Kg, const float* __restrict__ Vg,
    float* __restrict__ Spart, int split, int nchunks) {
  const int blk  = blockIdx.x;
  const int b    = blk / split;
  const int s    = blk - b * split;
  const int tid  = threadIdx.x;
  const int wv   = tid >> 6;
  const int lane = tid & 63;
  const int g    = lane >> 5;
  const int ln   = lane & 31;
  const int i0   = (wv >> 1) * 32;
  const int j0   = (wv & 1)  * 32;
  const int rowA = min(i0 + ln, NN - 1);   // clamp: dup loads, rows discarded
  const int rowB = min(j0 + ln, NN - 1);

  const size_t cbase = ((size_t)b * CH + (size_t)s * (nchunks * 16)) * NN;
  const float* Ka = Kg + cbase + (size_t)(g * 8) * NN + rowA;
  const float* Vb = Vg + cbase + (size_t)(g * 8) * NN + rowB;

  f32x16 acc;
  #pragma unroll
  for (int r = 0; r < 16; ++r) acc[r] = 0.f;

  #pragma unroll 2
  for (int kc = 0; kc < nchunks; ++kc) {
    const float* ka = Ka + (size_t)kc * 16 * NN;
    const float* vb = Vb + (size_t)kc * 16 * NN;
    float kx[8], vx[8];
    #pragma unroll
    for (int e = 0; e < 8; ++e) { kx[e] = ka[e * NN]; vx[e] = vb[e * NN]; }
    bf16x8 ah, bh;
    #pragma unroll
    for (int e = 0; e < 8; ++e) { ah[e] = f2bf(kx[e]); bh[e] = f2bf(vx[e]); }
    acc = __builtin_amdgcn_mfma_f32_32x32x16_bf16(ah, bh, acc, 0, 0, 0);
  }

  // C/D: col = lane&31, row = (r&3) + 8*(r>>2) + 4*(lane>>5)   [m74/m101]
  float* Sp = Spart + (size_t)blk * (NN * NN);
  const int j = j0 + ln;
  if (j < NN) {
    #pragma unroll
    for (int r = 0; r < 16; ++r) {
      const int i = i0 + (r & 3) + 8 * (r >> 2) + 4 * g;
      if (i < NN) Sp[i * NN + j] = acc[r];
    }
  }
}

// ------- Kernel 2: St[b][n][m] = bf16( sum_s Spart[m][n] ), [64][64] pad ----
__global__ __launch_bounds__(256) void sred_kernel(
    const float* __restrict__ Spart, unsigned short* __restrict__ St, int split) {
  const int b = blockIdx.x;
  const int t = threadIdx.x;
  for (int e = t; e < 64 * 64; e += 256) {
    const int n = e >> 6, m = e & 63;
    float v = 0.f;
    if (m < NN && n < NN) {
      for (int s = 0; s < split; ++s)
        v += Spart[(size_t)(b * split + s) * (NN * NN) + m * NN + n];
    }
    St[(size_t)b * 4096 + e] = (unsigned short)f2bf(v);
  }
}

// ------ Kernel 3: out = q @ S + v.  2 x 64-row tiles per block. -------------
__global__ __launch_bounds__(256) void qs_kernel(
    const float* __restrict__ Qg, const float* __restrict__ Vg,
    const unsigned short* __restrict__ St, float* __restrict__ Og) {
  const int blk  = blockIdx.x;            // 1024 = 128 batches x 8 tile-pairs
  const int b    = blk >> 3;
  const int pr   = blk & 7;
  const int tid  = threadIdx.x;
  const int wv   = tid >> 6;
  const int lane = tid & 63;
  const int g    = lane >> 5;
  const int ln   = lane & 31;
  const int i0   = (wv >> 1) * 32;
  const int j0   = (wv & 1)  * 32;

  __shared__ float Qt[2][64 * LDQ];       // 33.3 KB -> 4 blocks/CU

  // stage 128 q-rows transposed: Qt[t][m][r] = q[r0 + t*64 + r][m]; coalesced
  const size_t qbase = ((size_t)b * CH + (size_t)pr * 128) * NN;
  for (int idx = tid; idx < 2 * 64 * NN; idx += 256) {
    const int t = idx / (64 * NN);
    const int rem = idx - t * (64 * NN);
    const int r = rem / NN, m = rem - r * NN;
    Qt[t][m * LDQ + r] = Qg[qbase + idx];
  }
  for (int idx = tid; idx < 2 * (64 - NN) * LDQ; idx += 256) {  // zero m=49..63
    const int t = idx / ((64 - NN) * LDQ);
    Qt[t][NN * LDQ + (idx - t * ((64 - NN) * LDQ))] = 0.f;
  }
  __syncthreads();

  const int colQ = i0 + ln;                               // all 64 rows valid
  const int colB = min(j0 + ln, NN - 1);                  // clamp; cols junked
  const unsigned short* stb = St + (size_t)b * 4096 + colB * 64;
  const int j = j0 + ln;

  for (int t = 0; t < 2; ++t) {
    f32x16 acc;
    #pragma unroll
    for (int r = 0; r < 16; ++r) acc[r] = 0.f;

    #pragma unroll
    for (int kc = 0; kc < 4; ++kc) {
      const int m0 = kc * 16 + g * 8;
      bf16x8 ah;
      #pragma unroll
      for (int e = 0; e < 8; ++e)
        ah[e] = f2bf(Qt[t][(m0 + e) * LDQ + colQ]);       // lane-consecutive
      const bf16x8 bh = *(const bf16x8*)&stb[m0];         // 16-B, L1/L2-hot
      acc = __builtin_amdgcn_mfma_f32_32x32x16_bf16(ah, bh, acc, 0, 0, 0);
    }

    if (j < NN) {
      const size_t tb = qbase + (size_t)t * 64 * NN;
      #pragma unroll
      for (int r = 0; r < 16; ++r) {
        const int i = i0 + (r & 3) + 8 * (r >> 2) + 4 * g;
        const size_t off = tb + (size_t)i * NN + j;
        Og[off] = acc[r] + Vg[off];                        // coalesced per r
      }
    }
  }
}

extern "C" void kernel_launch(void* const* d_in, const int* in_sizes, int n_in,
                              void* d_out, int out_size, void* d_ws, size_t ws_size,
                              hipStream_t stream) {
  (void)in_sizes; (void)n_in; (void)out_size;
  const float* v1 = (const float*)d_in[0];
  const float* q1 = (const float*)d_in[1];
  const float* k1 = (const float*)d_in[2];
  float* out = (float*)d_out;

  int split = 8;                           // 9.83 MB spart + 1.05 MB St
  while (split > 1 &&
         (size_t)BATCH * split * NN * NN * 4 + (size_t)BATCH * 4096 * 2 > ws_size)
    split >>= 1;
  const int nchunks = CH / (split * 16);

  float* spart = (float*)d_ws;
  unsigned short* st = (unsigned short*)(spart + (size_t)BATCH * split * NN * NN);

  ktv_kernel<<<dim3(BATCH * split), dim3(256), 0, stream>>>(k1, v1, spart, split, nchunks);
  sred_kernel<<<dim3(BATCH), dim3(256), 0, stream>>>(spart, st, split);
  qs_kernel<<<dim3(BATCH * 8), dim3(256), 0, stream>>>(q1, v1, st, out);
}

// Round 11
// 51.142 us; speedup vs baseline: 1.6354x; 1.0050x over previous
//
#include <hip/hip_runtime.h>
#include <hip/hip_bf16.h>

// CAM: out = (q @ k^T) @ v + v  ==  q @ (k^T @ v) + v.   S[b] = k^T v is 49x49.
// Three kernels, pure-bf16 MFMA (RNE; absmax 8.0 vs threshold 27.68):
//   ktv : NO LDS, 1 MFMA/chunk, barrier-free streaming (R8-proven).
//   sred: partial-sum -> St = S^T bf16, zero-padded [64][64] per batch.
//   qs  : IO-OPTIMAL variant. ALL global traffic is flat float4 (1 KB/wave,
//         16-B aligned): q staged via flat loads -> LDS transpose; MFMA both
//         64-row tiles; accs -> LDS out-tile; flat float4 epilogue out=Ot+V.
//         Tests the theory that 196-B-row-granular IO was the ~40us floor.

#define BATCH  128
#define CH     1024
#define NN     49
#define LDQ    65     // f32 stride of Qt rows (conflict-free transpose)
#define LDO    52     // f32 stride of out-tile rows (2-way conflicts = free)

typedef short  bf16x8 __attribute__((ext_vector_type(8)));
typedef float  f32x16 __attribute__((ext_vector_type(16)));

__device__ __forceinline__ short f2bf(float x) {
  return __builtin_bit_cast(short, __float2bfloat16(x));   // RNE; pairs to cvt_pk
}

// ---------------- Kernel 1: Spart[b*split+s] = K-chunk^T @ V-chunk ----------
__global__ __launch_bounds__(256) void ktv_kernel(
    const float* __restrict__ Kg, const float* __restrict__ Vg,
    float* __restrict__ Spart, int split, int nchunks) {
  const int blk  = blockIdx.x;
  const int b    = blk / split;
  const int s    = blk - b * split;
  const int tid  = threadIdx.x;
  const int wv   = tid >> 6;
  const int lane = tid & 63;
  const int g    = lane >> 5;
  const int ln   = lane & 31;
  const int i0   = (wv >> 1) * 32;
  const int j0   = (wv & 1)  * 32;
  const int rowA = min(i0 + ln, NN - 1);   // clamp: dup loads, rows discarded
  const int rowB = min(j0 + ln, NN - 1);

  const size_t cbase = ((size_t)b * CH + (size_t)s * (nchunks * 16)) * NN;
  const float* Ka = Kg + cbase + (size_t)(g * 8) * NN + rowA;
  const float* Vb = Vg + cbase + (size_t)(g * 8) * NN + rowB;

  f32x16 acc;
  #pragma unroll
  for (int r = 0; r < 16; ++r) acc[r] = 0.f;

  #pragma unroll 2
  for (int kc = 0; kc < nchunks; ++kc) {
    const float* ka = Ka + (size_t)kc * 16 * NN;
    const float* vb = Vb + (size_t)kc * 16 * NN;
    float kx[8], vx[8];
    #pragma unroll
    for (int e = 0; e < 8; ++e) { kx[e] = ka[e * NN]; vx[e] = vb[e * NN]; }
    bf16x8 ah, bh;
    #pragma unroll
    for (int e = 0; e < 8; ++e) { ah[e] = f2bf(kx[e]); bh[e] = f2bf(vx[e]); }
    acc = __builtin_amdgcn_mfma_f32_32x32x16_bf16(ah, bh, acc, 0, 0, 0);
  }

  // C/D: col = lane&31, row = (r&3) + 8*(r>>2) + 4*(lane>>5)   [m74/m101]
  float* Sp = Spart + (size_t)blk * (NN * NN);
  const int j = j0 + ln;
  if (j < NN) {
    #pragma unroll
    for (int r = 0; r < 16; ++r) {
      const int i = i0 + (r & 3) + 8 * (r >> 2) + 4 * g;
      if (i < NN) Sp[i * NN + j] = acc[r];
    }
  }
}

// ------- Kernel 2: St[b][n][m] = bf16( sum_s Spart[m][n] ), [64][64] pad ----
__global__ __launch_bounds__(256) void sred_kernel(
    const float* __restrict__ Spart, unsigned short* __restrict__ St, int split) {
  const int b = blockIdx.x;
  const int t = threadIdx.x;
  for (int e = t; e < 64 * 64; e += 256) {
    const int n = e >> 6, m = e & 63;
    float v = 0.f;
    if (m < NN && n < NN) {
      for (int s = 0; s < split; ++s)
        v += Spart[(size_t)(b * split + s) * (NN * NN) + m * NN + n];
    }
    St[(size_t)b * 4096 + e] = (unsigned short)f2bf(v);
  }
}

// ------ Kernel 3: out = q @ S + v.  128 rows/block, flat-float4 global IO ---
#define NF4 1568      // 128*49/4 float4s per block

__global__ __launch_bounds__(256) void qs_kernel(
    const float* __restrict__ Qg, const float* __restrict__ Vg,
    const unsigned short* __restrict__ St, float* __restrict__ Og) {
  const int blk  = blockIdx.x;            // 1024 = 128 batches x 8 row-pairs
  const int b    = blk >> 3;
  const int pr   = blk & 7;
  const int tid  = threadIdx.x;
  const int wv   = tid >> 6;
  const int lane = tid & 63;
  const int g    = lane >> 5;
  const int ln   = lane & 31;
  const int i0   = (wv >> 1) * 32;
  const int j0   = (wv & 1)  * 32;

  __shared__ __align__(16) float sh[2 * 64 * LDQ];   // 33.3 KB; reused as Ot
  float* Ot = sh;                                    // 128*LDO = 6656 fits

  const size_t qbase = ((size_t)b * CH + (size_t)pr * 128) * NN;

  // ---- stage q: flat float4 loads (1 KB/wave, aligned), LDS transpose ----
  for (int fq = tid; fq < NF4; fq += 256) {
    const float4 qv = *(const float4*)&Qg[qbase + 4 * fq];
    const int f0 = 4 * fq;
    #pragma unroll
    for (int k = 0; k < 4; ++k) {
      const int f = f0 + k;
      const int r = f / NN, m = f - r * NN;
      sh[(r >> 6) * (64 * LDQ) + m * LDQ + (r & 63)] = ((const float*)&qv)[k];
    }
  }
  for (int e = tid; e < 2 * (64 - NN) * LDQ; e += 256) {   // zero pad m=49..63
    const int t = e / ((64 - NN) * LDQ);
    sh[t * (64 * LDQ) + NN * LDQ + (e - t * ((64 - NN) * LDQ))] = 0.f;
  }
  __syncthreads();

  // ---- MFMA both 64-row tiles (B = bf16 St, 16-B global loads, L2-hot) ----
  const int colQ = i0 + ln;
  const int colB = min(j0 + ln, NN - 1);
  const unsigned short* stb = St + (size_t)b * 4096 + colB * 64;
  bf16x8 bhv[4];
  #pragma unroll
  for (int kc = 0; kc < 4; ++kc) bhv[kc] = *(const bf16x8*)&stb[kc * 16 + g * 8];

  f32x16 acc0, acc1;
  #pragma unroll
  for (int r = 0; r < 16; ++r) { acc0[r] = 0.f; acc1[r] = 0.f; }

  #pragma unroll
  for (int kc = 0; kc < 4; ++kc) {
    const int m0 = kc * 16 + g * 8;
    bf16x8 a0, a1;
    #pragma unroll
    for (int e = 0; e < 8; ++e) {
      a0[e] = f2bf(sh[(m0 + e) * LDQ + colQ]);                   // tile 0
      a1[e] = f2bf(sh[64 * LDQ + (m0 + e) * LDQ + colQ]);        // tile 1
    }
    acc0 = __builtin_amdgcn_mfma_f32_32x32x16_bf16(a0, bhv[kc], acc0, 0, 0, 0);
    acc1 = __builtin_amdgcn_mfma_f32_32x32x16_bf16(a1, bhv[kc], acc1, 0, 0, 0);
  }
  __syncthreads();                 // all Qt reads consumed; safe to overwrite

  // ---- accs -> LDS out-tile Ot[i][j] (2-way bank conflicts = free) ----
  const int j = j0 + ln;
  if (j < NN) {
    #pragma unroll
    for (int r = 0; r < 16; ++r) {
      const int iq = i0 + (r & 3) + 8 * (r >> 2) + 4 * g;
      Ot[iq * LDO + j]        = acc0[r];
      Ot[(64 + iq) * LDO + j] = acc1[r];
    }
  }
  __syncthreads();

  // ---- flat float4 epilogue: out = Ot + v (dense, aligned, 1 KB/wave) ----
  for (int fq = tid; fq < NF4; fq += 256) {
    const int f0 = 4 * fq;
    const float4 vv = *(const float4*)&Vg[qbase + f0];
    float4 ov;
    #pragma unroll
    for (int k = 0; k < 4; ++k) {
      const int f = f0 + k;
      const int r = f / NN, m = f - r * NN;
      ((float*)&ov)[k] = Ot[r * LDO + m] + ((const float*)&vv)[k];
    }
    *(float4*)&Og[qbase + f0] = ov;
  }
}

extern "C" void kernel_launch(void* const* d_in, const int* in_sizes, int n_in,
                              void* d_out, int out_size, void* d_ws, size_t ws_size,
                              hipStream_t stream) {
  (void)in_sizes; (void)n_in; (void)out_size;
  const float* v1 = (const float*)d_in[0];
  const float* q1 = (const float*)d_in[1];
  const float* k1 = (const float*)d_in[2];
  float* out = (float*)d_out;

  int split = 8;                           // 9.83 MB spart + 1.05 MB St
  while (split > 1 &&
         (size_t)BATCH * split * NN * NN * 4 + (size_t)BATCH * 4096 * 2 > ws_size)
    split >>= 1;
  const int nchunks = CH / (split * 16);

  float* spart = (float*)d_ws;
  unsigned short* st = (unsigned short*)(spart + (size_t)BATCH * split * NN * NN);

  ktv_kernel<<<dim3(BATCH * split), dim3(256), 0, stream>>>(k1, v1, spart, split, nchunks);
  sred_kernel<<<dim3(BATCH), dim3(256), 0, stream>>>(spart, st, split);
  qs_kernel<<<dim3(BATCH * 8), dim3(256), 0, stream>>>(q1, v1, st, out);
}